// Round 4
// baseline (297.404 us; speedup 1.0000x reference)
//
#include <hip/hip_runtime.h>

#define N_NODES  100000
#define N_EDGES  1600000
#define D        128
#define NG       64
#define NC       10
#define NBMAX    512      // gemm grid (2 blocks/CU)
#define TILE     64       // nodes per LDS tile

typedef unsigned int uint;
typedef unsigned long long ull;

static_assert(N_EDGES % 4 == 0, "int4 edge loads");

// ---------------------------------------------------------------------------
// Kernel 0: zero cnt (u8-packed counts) + counts[64] (contiguous region).
// ---------------------------------------------------------------------------
__global__ __launch_bounds__(256) void zero_kernel(uint4* __restrict__ p, int n4)
{
    int i = blockIdx.x * 256 + threadIdx.x;
    const int stride = gridDim.x * 256;
    const uint4 z = {0u, 0u, 0u, 0u};
    for (; i < n4; i += stride) p[i] = z;
}

// ---------------------------------------------------------------------------
// Kernel 1: cnt[n][g] = #edges (src=n, batch[dst]=g), 4 graphs packed per u32
// (max per cell <= out-degree << 255). 4 edges/thread via int4; native int
// atomics are fire-and-forget (no CAS loop, no latency chain).
// ---------------------------------------------------------------------------
__global__ __launch_bounds__(256) void edge_count_kernel(
    const int* __restrict__ ei, const int* __restrict__ batch,
    uint* __restrict__ cnt)
{
    const int e0 = (blockIdx.x * 256 + threadIdx.x) * 4;
    if (e0 >= N_EDGES) return;
    const int4 s4 = *reinterpret_cast<const int4*>(ei + e0);
    const int4 d4 = *reinterpret_cast<const int4*>(ei + N_EDGES + e0);
    const int g0 = batch[d4.x], g1 = batch[d4.y];
    const int g2 = batch[d4.z], g3 = batch[d4.w];
    atomicAdd(&cnt[(size_t)s4.x * 16 + (g0 >> 2)], 1u << ((g0 & 3) * 8));
    atomicAdd(&cnt[(size_t)s4.y * 16 + (g1 >> 2)], 1u << ((g1 & 3) * 8));
    atomicAdd(&cnt[(size_t)s4.z * 16 + (g2 >> 2)], 1u << ((g2 & 3) * 8));
    atomicAdd(&cnt[(size_t)s4.w * 16 + (g3 >> 2)], 1u << ((g3 & 3) * 8));
}

// ---------------------------------------------------------------------------
// Kernel 2: per-graph node counts via sorted-run detection (few atomics).
// ---------------------------------------------------------------------------
__global__ __launch_bounds__(256) void count_kernel(
    const int* __restrict__ batch, int* __restrict__ counts)
{
    const int n = blockIdx.x * 256 + threadIdx.x;
    if (n >= N_NODES) return;
    const int lane = threadIdx.x & 63;
    const int g = batch[n];
    const bool lead = (n == 0) || (lane == 0) || (batch[n - 1] != g);
    const ull b = __ballot(lead);
    if (lead) {
        const ull higher = (lane == 63) ? 0ull : (b >> (lane + 1));
        int end = higher ? (lane + 1 + (__ffsll(higher) - 1)) : 64;
        const int wb = n - lane;
        int nv = N_NODES - wb; if (nv > 64) nv = 64;
        if (end > nv) end = nv;
        atomicAdd(&counts[g], end - lane);
    }
}

// ---------------------------------------------------------------------------
// Kernel 3: dense GEMM  agg[g][d] = sum_n cnt[n][g]*x[n][d]  (+ self-sums via
// sorted run-sum). 512 threads = 8 waves; wave q owns graphs 8q..8q+7; thread
// (q, d2=t&63) owns dims {2*d2, 2*d2+1}. Per node per wave: one b64 x-read +
// two broadcast b128 cnt-reads -> 16 MACs. No atomics. 2 blocks/CU.
// ---------------------------------------------------------------------------
#define FLUSH_X()                                                       \
    if ((cur_g >> 3) == q) {                                            \
        switch (cur_g & 7) {                                            \
            case 0: aX[0]  += rsx; aX[1]  += rsy; break;                \
            case 1: aX[2]  += rsx; aX[3]  += rsy; break;                \
            case 2: aX[4]  += rsx; aX[5]  += rsy; break;                \
            case 3: aX[6]  += rsx; aX[7]  += rsy; break;                \
            case 4: aX[8]  += rsx; aX[9]  += rsy; break;                \
            case 5: aX[10] += rsx; aX[11] += rsy; break;                \
            case 6: aX[12] += rsx; aX[13] += rsy; break;                \
            case 7: aX[14] += rsx; aX[15] += rsy; break;                \
        }                                                               \
    }

__global__ __launch_bounds__(512, 4) void gemm_kernel(
    const float* __restrict__ x, const uint* __restrict__ cnt,
    const int* __restrict__ batch,
    float* __restrict__ partA, float* __restrict__ partX, int NBe)
{
    __shared__ float xs[TILE * D];       // 32 KB
    __shared__ float cs[TILE * 68];      // 17.4 KB (16B-aligned padded rows)
    __shared__ int   bs[TILE];

    const int t  = threadIdx.x;
    const int d2 = t & 63;
    const int q  = t >> 6;               // wave-uniform, 0..7

    float aA[16], aX[16];
    #pragma unroll
    for (int i = 0; i < 16; ++i) { aA[i] = 0.f; aX[i] = 0.f; }
    float rsx = 0.f, rsy = 0.f;
    int cur_g = -1;

    const int ntiles = (N_NODES + TILE - 1) / TILE;
    for (int tb = blockIdx.x; tb < ntiles; tb += NBe) {
        const int base = tb * TILE;
        const int nvalid = min(TILE, N_NODES - base);

        // stage x: 4 float4/thread, coalesced
        #pragma unroll
        for (int k = 0; k < 4; ++k) {
            const int f4 = t + k * 512;
            const int n  = f4 >> 5;
            const int c4 = f4 & 31;
            float4 v = make_float4(0.f, 0.f, 0.f, 0.f);
            if (n < nvalid)
                v = *reinterpret_cast<const float4*>(x + (size_t)(base + n) * D + c4 * 4);
            reinterpret_cast<float4*>(xs)[f4] = v;
        }
        // stage cnt: 2 u32/thread -> 8 floats
        #pragma unroll
        for (int k = 0; k < 2; ++k) {
            const int idx = t + k * 512;
            const int node = idx >> 4, slot = idx & 15;
            uint cv = 0u;
            if (node < nvalid) cv = cnt[(size_t)(base + node) * 16 + slot];
            float* cb = cs + node * 68 + slot * 4;
            cb[0] = (float)(cv & 255u);
            cb[1] = (float)((cv >> 8) & 255u);
            cb[2] = (float)((cv >> 16) & 255u);
            cb[3] = (float)(cv >> 24);
        }
        if (t < TILE) bs[t] = (t < nvalid) ? batch[base + t] : -1;
        __syncthreads();

        #pragma unroll 8
        for (int n = 0; n < TILE; ++n) {
            const float2 v  = reinterpret_cast<const float2*>(xs)[n * 64 + d2];
            const float4 c0 = *reinterpret_cast<const float4*>(cs + n * 68 + q * 8);
            const float4 c1 = *reinterpret_cast<const float4*>(cs + n * 68 + q * 8 + 4);
            const int bg = bs[n];
            if (bg != cur_g) {                  // wave-uniform, rare
                FLUSH_X();
                rsx = 0.f; rsy = 0.f; cur_g = bg;
            }
            rsx += v.x; rsy += v.y;
            aA[0]  += c0.x * v.x; aA[1]  += c0.x * v.y;
            aA[2]  += c0.y * v.x; aA[3]  += c0.y * v.y;
            aA[4]  += c0.z * v.x; aA[5]  += c0.z * v.y;
            aA[6]  += c0.w * v.x; aA[7]  += c0.w * v.y;
            aA[8]  += c1.x * v.x; aA[9]  += c1.x * v.y;
            aA[10] += c1.y * v.x; aA[11] += c1.y * v.y;
            aA[12] += c1.z * v.x; aA[13] += c1.z * v.y;
            aA[14] += c1.w * v.x; aA[15] += c1.w * v.y;
        }
        FLUSH_X();                               // tile-end flush
        rsx = 0.f; rsy = 0.f;
        __syncthreads();
    }

    float* pa = partA + (size_t)blockIdx.x * (NG * D);
    float* px = partX + (size_t)blockIdx.x * (NG * D);
    #pragma unroll
    for (int k = 0; k < 8; ++k) {
        reinterpret_cast<float2*>(pa + (size_t)(q * 8 + k) * D)[d2] =
            make_float2(aA[2 * k], aA[2 * k + 1]);
        reinterpret_cast<float2*>(px + (size_t)(q * 8 + k) * D)[d2] =
            make_float2(aX[2 * k], aX[2 * k + 1]);
    }
}

// ---------------------------------------------------------------------------
// Kernel 4: partial reduction, fully coalesced. 256 blocks: column-block
// (cb=b&63 -> 256 columns of the 16384-wide [A|X] space) x partial-chunk
// (pc=b>>6 of 4). Writes tmp2[pc][16384].
// ---------------------------------------------------------------------------
__global__ __launch_bounds__(256) void reduce1_kernel(
    const float* __restrict__ partA, const float* __restrict__ partX,
    float* __restrict__ tmp2, int NBe)
{
    const int cb = blockIdx.x & 63;
    const int pc = blockIdx.x >> 6;
    const int c  = cb * 256 + threadIdx.x;       // 0..16383
    const float* __restrict__ srcp =
        (c < NG * D) ? (partA + c) : (partX + (c - NG * D));
    const int chunk = (NBe + 3) >> 2;
    const int p0 = pc * chunk;
    int p1 = p0 + chunk; if (p1 > NBe) p1 = NBe;
    float s = 0.f;
    #pragma unroll 8
    for (int p = p0; p < p1; ++p) s += srcp[(size_t)p * (NG * D)];
    tmp2[pc * (2 * NG * D) + c] = s;
}

// ---------------------------------------------------------------------------
// Kernel 5: final 4-way sum + matvec pair + classifier. Block = graph.
// ---------------------------------------------------------------------------
__global__ __launch_bounds__(128) void final_kernel(
    const float* __restrict__ tmp2, const int* __restrict__ counts,
    const float* __restrict__ w_rel, const float* __restrict__ b_rel,
    const float* __restrict__ w_root,
    const float* __restrict__ w_lin, const float* __restrict__ b_lin,
    float* __restrict__ out)
{
    const int g = blockIdx.x;
    const int t = threadIdx.x;   // 0..127

    __shared__ float agg_s[D], x_s[D], p_s[D];
    float a = 0.f, xsum = 0.f;
    #pragma unroll
    for (int j = 0; j < 4; ++j) {
        a    += tmp2[j * (2 * NG * D) + g * D + t];
        xsum += tmp2[j * (2 * NG * D) + NG * D + g * D + t];
    }
    agg_s[t] = a; x_s[t] = xsum;
    __syncthreads();

    const float cn = (float)counts[g];
    float hj = b_rel[t] * cn;
    const float* __restrict__ wr = w_rel  + (size_t)t * D;
    const float* __restrict__ wo = w_root + (size_t)t * D;
    #pragma unroll 8
    for (int d0 = 0; d0 < D; ++d0) hj += agg_s[d0] * wr[d0] + x_s[d0] * wo[d0];
    p_s[t] = hj / fmaxf(cn, 1.f);
    __syncthreads();

    if (t < NC) {
        const float* __restrict__ wl = w_lin + (size_t)t * D;
        float o = b_lin[t];
        #pragma unroll 8
        for (int d0 = 0; d0 < D; ++d0) o += p_s[d0] * wl[d0];
        out[g * NC + t] = o;
    }
}

extern "C" void kernel_launch(void* const* d_in, const int* in_sizes, int n_in,
                              void* d_out, int out_size, void* d_ws, size_t ws_size,
                              hipStream_t stream)
{
    const float* x      = (const float*)d_in[0];
    const int*   ei     = (const int*)  d_in[1];
    const int*   batch  = (const int*)  d_in[2];
    const float* w_rel  = (const float*)d_in[3];
    const float* b_rel  = (const float*)d_in[4];
    const float* w_root = (const float*)d_in[5];
    const float* w_lin  = (const float*)d_in[6];
    const float* b_lin  = (const float*)d_in[7];
    float* out = (float*)d_out;

    // ws layout: cnt (6.4 MB) | counts (64 int) | tmp2 (256 KB) | partA | partX
    const size_t cntf  = (size_t)N_NODES * 16;       // u32 units
    const size_t tmp2f = 4 * (size_t)(2 * NG * D);
    uint*  cnt    = (uint*)d_ws;
    int*   counts = (int*)(cnt + cntf);
    float* tmp2   = (float*)(counts + 64);
    float* partA  = tmp2 + tmp2f;

    const size_t availf = ws_size / sizeof(float);
    const size_t headf  = cntf + 64 + tmp2f;
    int NBe = NBMAX;
    if (headf + (size_t)NBe * 2 * NG * D > availf) {
        long long rem = (long long)availf - (long long)headf;
        long long nb  = rem / (2 * NG * D);
        NBe = (nb < 1) ? 1 : (int)nb;
    }
    float* partX = partA + (size_t)NBe * NG * D;

    const int zero_n4 = (int)((cntf * 4 + 256) / 16);
    zero_kernel<<<1024, 256, 0, stream>>>((uint4*)d_ws, zero_n4);
    edge_count_kernel<<<(N_EDGES / 4 + 255) / 256, 256, 0, stream>>>(ei, batch, cnt);
    count_kernel<<<(N_NODES + 255) / 256, 256, 0, stream>>>(batch, counts);
    gemm_kernel<<<NBe, 512, 0, stream>>>(x, cnt, batch, partA, partX, NBe);
    reduce1_kernel<<<256, 256, 0, stream>>>(partA, partX, tmp2, NBe);
    final_kernel<<<NG, 128, 0, stream>>>(tmp2, counts,
                                         w_rel, b_rel, w_root, w_lin, b_lin, out);
}

// Round 5
// 148.616 us; speedup vs baseline: 2.0012x; 2.0012x over previous
//
#include <hip/hip_runtime.h>

#define N_NODES  100000
#define N_EDGES  1600000
#define D        128
#define NG       64
#define NC       10
#define NBMAX    512      // gemm grid: 2 blocks/CU (1024 thr each)
#define TILE     64       // nodes per LDS tile

typedef unsigned int uint;
typedef unsigned long long ull;

static_assert(N_EDGES % 4 == 0, "int4 edge loads");

// ---------------------------------------------------------------------------
// Kernel 0: zero cnt (u8-packed counts) + counts[64] (contiguous region).
// ---------------------------------------------------------------------------
__global__ __launch_bounds__(256) void zero_kernel(uint4* __restrict__ p, int n4)
{
    int i = blockIdx.x * 256 + threadIdx.x;
    const int stride = gridDim.x * 256;
    const uint4 z = {0u, 0u, 0u, 0u};
    for (; i < n4; i += stride) p[i] = z;
}

// ---------------------------------------------------------------------------
// Kernel 1: cnt[n][g] = #edges (src=n, batch[dst]=g), 4 graphs packed per u32
// (max per cell <= out-degree << 255). 4 edges/thread via int4; native int
// atomics are fire-and-forget (no CAS loop, no latency chain).
// ---------------------------------------------------------------------------
__global__ __launch_bounds__(256) void edge_count_kernel(
    const int* __restrict__ ei, const int* __restrict__ batch,
    uint* __restrict__ cnt)
{
    const int e0 = (blockIdx.x * 256 + threadIdx.x) * 4;
    if (e0 >= N_EDGES) return;
    const int4 s4 = *reinterpret_cast<const int4*>(ei + e0);
    const int4 d4 = *reinterpret_cast<const int4*>(ei + N_EDGES + e0);
    const int g0 = batch[d4.x], g1 = batch[d4.y];
    const int g2 = batch[d4.z], g3 = batch[d4.w];
    atomicAdd(&cnt[(size_t)s4.x * 16 + (g0 >> 2)], 1u << ((g0 & 3) * 8));
    atomicAdd(&cnt[(size_t)s4.y * 16 + (g1 >> 2)], 1u << ((g1 & 3) * 8));
    atomicAdd(&cnt[(size_t)s4.z * 16 + (g2 >> 2)], 1u << ((g2 & 3) * 8));
    atomicAdd(&cnt[(size_t)s4.w * 16 + (g3 >> 2)], 1u << ((g3 & 3) * 8));
}

// ---------------------------------------------------------------------------
// Kernel 2: per-graph node counts via sorted-run detection (few atomics).
// ---------------------------------------------------------------------------
__global__ __launch_bounds__(256) void count_kernel(
    const int* __restrict__ batch, int* __restrict__ counts)
{
    const int n = blockIdx.x * 256 + threadIdx.x;
    if (n >= N_NODES) return;
    const int lane = threadIdx.x & 63;
    const int g = batch[n];
    const bool lead = (n == 0) || (lane == 0) || (batch[n - 1] != g);
    const ull b = __ballot(lead);
    if (lead) {
        const ull higher = (lane == 63) ? 0ull : (b >> (lane + 1));
        int end = higher ? (lane + 1 + (__ffsll(higher) - 1)) : 64;
        const int wb = n - lane;
        int nv = N_NODES - wb; if (nv > 64) nv = 64;
        if (end > nv) end = nv;
        atomicAdd(&counts[g], end - lane);
    }
}

// ---------------------------------------------------------------------------
// Kernel 3: dense GEMM  agg[g][d] = sum_n cnt[n][g]*x[n][d]  (+ self-sums via
// sorted run-sum). Round-3-proven register shape: 1024 threads = 16 waves;
// wave q (=t>>6, wave-uniform) owns graphs 4q..4q+3; thread (q, d2=t&63) owns
// dims {2*d2, 2*d2+1}. 18 live accumulator floats -> VGPR=32, zero spill.
// Per node per wave: one b64 x-read + one broadcast b128 cnt-read -> 8 MACs.
// Grid 512 = 2 blocks/CU so staging/barriers of one block overlap compute of
// the other. No atomics.
// ---------------------------------------------------------------------------
__global__ __launch_bounds__(1024) void gemm_kernel(
    const float* __restrict__ x, const uint* __restrict__ cnt,
    const int* __restrict__ batch,
    float* __restrict__ partA, float* __restrict__ partX, int NBe)
{
    __shared__ float xs[TILE * D];       // [n][d], 32 KB
    __shared__ float cs[TILE * 68];      // [n][g] padded rows (16B-aligned)
    __shared__ int   bs[TILE];

    const int t  = threadIdx.x;
    const int d2 = t & 63;
    const int q  = t >> 6;               // wave-uniform, 0..15

    float a0x=0,a0y=0,a1x=0,a1y=0,a2x=0,a2y=0,a3x=0,a3y=0;
    float x0x=0,x0y=0,x1x=0,x1y=0,x2x=0,x2y=0,x3x=0,x3y=0;
    float rsx=0.f, rsy=0.f;
    int cur_g = -1;

    const int ntiles = (N_NODES + TILE - 1) / TILE;
    for (int tb = blockIdx.x; tb < ntiles; tb += NBe) {
        const int base = tb * TILE;
        const int nvalid = min(TILE, N_NODES - base);

        // stage x: 2 float4 per thread, coalesced global, consecutive LDS b128
        #pragma unroll
        for (int k = 0; k < 2; ++k) {
            const int f4 = t + k * 1024;
            const int n  = f4 >> 5;
            const int c4 = f4 & 31;
            float4 v = make_float4(0.f, 0.f, 0.f, 0.f);
            if (n < nvalid)
                v = *reinterpret_cast<const float4*>(x + (size_t)(base + n) * D + c4 * 4);
            reinterpret_cast<float4*>(xs)[f4] = v;
        }
        // stage cnt: 1 u32 per thread -> 4 floats
        {
            const int node = t >> 4, slot = t & 15;
            uint cv = 0u;
            if (node < nvalid) cv = cnt[(size_t)(base + node) * 16 + slot];
            float* cb = cs + node * 68 + slot * 4;
            cb[0] = (float)(cv & 255u);
            cb[1] = (float)((cv >> 8) & 255u);
            cb[2] = (float)((cv >> 16) & 255u);
            cb[3] = (float)(cv >> 24);
        }
        if (t < TILE) bs[t] = (t < nvalid) ? batch[base + t] : -1;
        __syncthreads();

        #pragma unroll 4
        for (int n = 0; n < TILE; ++n) {
            const float2 v = reinterpret_cast<const float2*>(xs)[n * 64 + d2];
            const float4 c = *reinterpret_cast<const float4*>(cs + n * 68 + q * 4);
            const int bg = bs[n];
            if (bg != cur_g) {                       // wave-uniform branch
                if ((cur_g >> 2) == q) {             // wave-uniform
                    switch (cur_g & 3) {
                        case 0: x0x += rsx; x0y += rsy; break;
                        case 1: x1x += rsx; x1y += rsy; break;
                        case 2: x2x += rsx; x2y += rsy; break;
                        case 3: x3x += rsx; x3y += rsy; break;
                    }
                }
                rsx = 0.f; rsy = 0.f;
                cur_g = bg;
            }
            rsx += v.x; rsy += v.y;
            a0x += c.x * v.x; a0y += c.x * v.y;
            a1x += c.y * v.x; a1y += c.y * v.y;
            a2x += c.z * v.x; a2y += c.z * v.y;
            a3x += c.w * v.x; a3y += c.w * v.y;
        }
        // tile-end flush (next tile is a distant node range)
        if ((cur_g >> 2) == q) {
            switch (cur_g & 3) {
                case 0: x0x += rsx; x0y += rsy; break;
                case 1: x1x += rsx; x1y += rsy; break;
                case 2: x2x += rsx; x2y += rsy; break;
                case 3: x3x += rsx; x3y += rsy; break;
            }
        }
        rsx = 0.f; rsy = 0.f;
        __syncthreads();
    }

    float* pa = partA + (size_t)blockIdx.x * (NG * D);
    float* px = partX + (size_t)blockIdx.x * (NG * D);
    const int gb = q * 4;
    reinterpret_cast<float2*>(pa + (size_t)(gb + 0) * D)[d2] = make_float2(a0x, a0y);
    reinterpret_cast<float2*>(pa + (size_t)(gb + 1) * D)[d2] = make_float2(a1x, a1y);
    reinterpret_cast<float2*>(pa + (size_t)(gb + 2) * D)[d2] = make_float2(a2x, a2y);
    reinterpret_cast<float2*>(pa + (size_t)(gb + 3) * D)[d2] = make_float2(a3x, a3y);
    reinterpret_cast<float2*>(px + (size_t)(gb + 0) * D)[d2] = make_float2(x0x, x0y);
    reinterpret_cast<float2*>(px + (size_t)(gb + 1) * D)[d2] = make_float2(x1x, x1y);
    reinterpret_cast<float2*>(px + (size_t)(gb + 2) * D)[d2] = make_float2(x2x, x2y);
    reinterpret_cast<float2*>(px + (size_t)(gb + 3) * D)[d2] = make_float2(x3x, x3y);
}

// ---------------------------------------------------------------------------
// Kernel 4: partial reduction, fully coalesced. 256 blocks: column-block
// (cb=b&63 -> 256 columns of the 16384-wide [A|X] space) x partial-chunk
// (pc=b>>6 of 4). Writes tmp2[pc][16384].
// ---------------------------------------------------------------------------
__global__ __launch_bounds__(256) void reduce1_kernel(
    const float* __restrict__ partA, const float* __restrict__ partX,
    float* __restrict__ tmp2, int NBe)
{
    const int cb = blockIdx.x & 63;
    const int pc = blockIdx.x >> 6;
    const int c  = cb * 256 + threadIdx.x;       // 0..16383
    const float* __restrict__ srcp =
        (c < NG * D) ? (partA + c) : (partX + (c - NG * D));
    const int chunk = (NBe + 3) >> 2;
    const int p0 = pc * chunk;
    int p1 = p0 + chunk; if (p1 > NBe) p1 = NBe;
    float s = 0.f;
    #pragma unroll 8
    for (int p = p0; p < p1; ++p) s += srcp[(size_t)p * (NG * D)];
    tmp2[pc * (2 * NG * D) + c] = s;
}

// ---------------------------------------------------------------------------
// Kernel 5: final 4-way sum + matvec pair + classifier. Block = graph.
// ---------------------------------------------------------------------------
__global__ __launch_bounds__(128) void final_kernel(
    const float* __restrict__ tmp2, const int* __restrict__ counts,
    const float* __restrict__ w_rel, const float* __restrict__ b_rel,
    const float* __restrict__ w_root,
    const float* __restrict__ w_lin, const float* __restrict__ b_lin,
    float* __restrict__ out)
{
    const int g = blockIdx.x;
    const int t = threadIdx.x;   // 0..127

    __shared__ float agg_s[D], x_s[D], p_s[D];
    float a = 0.f, xsum = 0.f;
    #pragma unroll
    for (int j = 0; j < 4; ++j) {
        a    += tmp2[j * (2 * NG * D) + g * D + t];
        xsum += tmp2[j * (2 * NG * D) + NG * D + g * D + t];
    }
    agg_s[t] = a; x_s[t] = xsum;
    __syncthreads();

    const float cn = (float)counts[g];
    float hj = b_rel[t] * cn;
    const float* __restrict__ wr = w_rel  + (size_t)t * D;
    const float* __restrict__ wo = w_root + (size_t)t * D;
    #pragma unroll 8
    for (int d0 = 0; d0 < D; ++d0) hj += agg_s[d0] * wr[d0] + x_s[d0] * wo[d0];
    p_s[t] = hj / fmaxf(cn, 1.f);
    __syncthreads();

    if (t < NC) {
        const float* __restrict__ wl = w_lin + (size_t)t * D;
        float o = b_lin[t];
        #pragma unroll 8
        for (int d0 = 0; d0 < D; ++d0) o += p_s[d0] * wl[d0];
        out[g * NC + t] = o;
    }
}

extern "C" void kernel_launch(void* const* d_in, const int* in_sizes, int n_in,
                              void* d_out, int out_size, void* d_ws, size_t ws_size,
                              hipStream_t stream)
{
    const float* x      = (const float*)d_in[0];
    const int*   ei     = (const int*)  d_in[1];
    const int*   batch  = (const int*)  d_in[2];
    const float* w_rel  = (const float*)d_in[3];
    const float* b_rel  = (const float*)d_in[4];
    const float* w_root = (const float*)d_in[5];
    const float* w_lin  = (const float*)d_in[6];
    const float* b_lin  = (const float*)d_in[7];
    float* out = (float*)d_out;

    // ws layout: cnt (6.4 MB) | counts (64 int) | tmp2 (256 KB) | partA | partX
    const size_t cntf  = (size_t)N_NODES * 16;       // u32 units
    const size_t tmp2f = 4 * (size_t)(2 * NG * D);
    uint*  cnt    = (uint*)d_ws;
    int*   counts = (int*)(cnt + cntf);
    float* tmp2   = (float*)(counts + 64);
    float* partA  = tmp2 + tmp2f;

    const size_t availf = ws_size / sizeof(float);
    const size_t headf  = cntf + 64 + tmp2f;
    int NBe = NBMAX;
    if (headf + (size_t)NBe * 2 * NG * D > availf) {
        long long rem = (long long)availf - (long long)headf;
        long long nb  = rem / (2 * NG * D);
        NBe = (nb < 1) ? 1 : (int)nb;
    }
    float* partX = partA + (size_t)NBe * NG * D;

    const int zero_n4 = (int)((cntf * 4 + 256) / 16);
    zero_kernel<<<1024, 256, 0, stream>>>((uint4*)d_ws, zero_n4);
    edge_count_kernel<<<(N_EDGES / 4 + 255) / 256, 256, 0, stream>>>(ei, batch, cnt);
    count_kernel<<<(N_NODES + 255) / 256, 256, 0, stream>>>(batch, counts);
    gemm_kernel<<<NBe, 1024, 0, stream>>>(x, cnt, batch, partA, partX, NBe);
    reduce1_kernel<<<256, 256, 0, stream>>>(partA, partX, tmp2, NBe);
    final_kernel<<<NG, 128, 0, stream>>>(tmp2, counts,
                                         w_rel, b_rel, w_root, w_lin, b_lin, out);
}